// Round 1
// baseline (15766.989 us; speedup 1.0000x reference)
//
#include <hip/hip_runtime.h>
#include <hip/hip_bf16.h>

#define Bb   64
#define Tt   512
#define INN  256
#define HH   1024
#define OUTN 512

typedef __attribute__((ext_vector_type(8))) short bf16x8;
typedef __attribute__((ext_vector_type(4))) float f32x4;

__device__ __forceinline__ unsigned short f2b(float f) {
  unsigned u = __float_as_uint(f);
  u += 0x7FFFu + ((u >> 16) & 1u);
  return (unsigned short)(u >> 16);
}

// fp32 -> bf16 (RNE), vectorized x4
__global__ void cvt4(const float* __restrict__ in, unsigned short* __restrict__ out, int n4) {
  int i = blockIdx.x * blockDim.x + threadIdx.x;
  if (i >= n4) return;
  float4 v = ((const float4*)in)[i];
  ushort4 o;
  o.x = f2b(v.x); o.y = f2b(v.y); o.z = f2b(v.z); o.w = f2b(v.w);
  ((ushort4*)out)[i] = o;
}

__global__ void addv(const float* __restrict__ a, const float* __restrict__ b,
                     float* __restrict__ o, int n) {
  int i = blockIdx.x * blockDim.x + threadIdx.x;
  if (i < n) o[i] = a[i] + b[i];
}

// Generic MFMA GEMM: C[m,n] = sum_k A[m,k] * W[n,k]  (W stored (N,K) row-major)
// One wave (64 threads) per block computes a 16(M) x 64(N) tile.
// MODE 0 (xproj): C_bf16 = acc + bias[n]
// MODE 1 (step):  C_bf16 = tanh(acc + (float)C_bf16[m,n])   (in-place over xproj slot)
// MODE 2 (fc):    C_f32  = acc + bias[n]
enum { MODE_XP = 0, MODE_STEP = 1, MODE_FC = 2 };

template<int MODE>
__global__ void gemm16(const __hip_bfloat16* __restrict__ A, long lda,
                       const __hip_bfloat16* __restrict__ W, int ldw,
                       const float* __restrict__ bias,
                       void* __restrict__ C, long ldc, int nk)
{
  const int l    = threadIdx.x;
  const int m0   = blockIdx.x << 4;
  const int n0   = blockIdx.y << 6;
  const int r16  = l & 15;
  const int koff = (l >> 4) << 3;   // 8 contiguous bf16 per lane along K

  const short* Ap = (const short*)A + (long)(m0 + r16) * lda + koff;
  const short* Wp = (const short*)W;
  const long  w0  = (long)(n0 + r16) * (long)ldw + koff;
  const long  wS  = (long)ldw << 4;  // 16 rows of W

  f32x4 acc0 = {0,0,0,0}, acc1 = {0,0,0,0}, acc2 = {0,0,0,0}, acc3 = {0,0,0,0};

  for (int kc = 0; kc < nk; kc += 32) {
    bf16x8 a  = *(const bf16x8*)(Ap + kc);
    bf16x8 b0 = *(const bf16x8*)(Wp + w0 +          kc);
    bf16x8 b1 = *(const bf16x8*)(Wp + w0 + wS     + kc);
    bf16x8 b2 = *(const bf16x8*)(Wp + w0 + 2 * wS + kc);
    bf16x8 b3 = *(const bf16x8*)(Wp + w0 + 3 * wS + kc);
    acc0 = __builtin_amdgcn_mfma_f32_16x16x32_bf16(a, b0, acc0, 0, 0, 0);
    acc1 = __builtin_amdgcn_mfma_f32_16x16x32_bf16(a, b1, acc1, 0, 0, 0);
    acc2 = __builtin_amdgcn_mfma_f32_16x16x32_bf16(a, b2, acc2, 0, 0, 0);
    acc3 = __builtin_amdgcn_mfma_f32_16x16x32_bf16(a, b3, acc3, 0, 0, 0);
  }

  // C/D layout: col = lane&15, row = (lane>>4)*4 + reg   [measured m89/m91]
  const int col = l & 15;
  const int rb  = (l >> 4) << 2;

#define EPILOG(FIDX, ACC)                                                     \
  {                                                                           \
    const int n = n0 + (FIDX << 4) + col;                                     \
    _Pragma("unroll")                                                         \
    for (int r = 0; r < 4; ++r) {                                             \
      const long idx = (long)(m0 + rb + r) * ldc + n;                         \
      float v = ACC[r];                                                       \
      if constexpr (MODE == MODE_XP) {                                        \
        v += bias[n];                                                         \
        ((unsigned short*)C)[idx] = f2b(v);                                   \
      } else if constexpr (MODE == MODE_STEP) {                               \
        v += __bfloat162float(((const __hip_bfloat16*)C)[idx]);               \
        v = tanhf(v);                                                         \
        ((unsigned short*)C)[idx] = f2b(v);                                   \
      } else {                                                                \
        v += bias[n];                                                         \
        ((float*)C)[idx] = v;                                                 \
      }                                                                       \
    }                                                                         \
  }

  EPILOG(0, acc0)
  EPILOG(1, acc1)
  EPILOG(2, acc2)
  EPILOG(3, acc3)
#undef EPILOG
}

extern "C" void kernel_launch(void* const* d_in, const int* in_sizes, int n_in,
                              void* d_out, int out_size, void* d_ws, size_t ws_size,
                              hipStream_t stream)
{
  const float* x   = (const float*)d_in[0];
  const float* Wx0 = (const float*)d_in[1];
  const float* bx0 = (const float*)d_in[2];
  const float* Wh0 = (const float*)d_in[3];
  const float* bh0 = (const float*)d_in[4];
  const float* Wx1 = (const float*)d_in[5];
  const float* bx1 = (const float*)d_in[6];
  const float* Wh1 = (const float*)d_in[7];
  const float* bh1 = (const float*)d_in[8];
  const float* Wfc = (const float*)d_in[9];
  const float* bfc = (const float*)d_in[10];

  char* ws = (char*)d_ws;
  // ws layout (bytes)
  const long SZ_XBF = (long)Bb * Tt * INN * 2;    //  16,777,216
  const long SZ_P   = (long)Bb * Tt * HH  * 2;    //  67,108,864
  __hip_bfloat16* xbf   = (__hip_bfloat16*)(ws);
  __hip_bfloat16* P0    = (__hip_bfloat16*)(ws + SZ_XBF);
  __hip_bfloat16* P1    = (__hip_bfloat16*)(ws + SZ_XBF + SZ_P);
  __hip_bfloat16* Wx0b  = (__hip_bfloat16*)(ws + SZ_XBF + 2 * SZ_P);
  __hip_bfloat16* Wh0b  = (__hip_bfloat16*)((char*)Wx0b + (long)HH * INN * 2);
  __hip_bfloat16* Wx1b  = (__hip_bfloat16*)((char*)Wh0b + (long)HH * HH * 2);
  __hip_bfloat16* Wh1b  = (__hip_bfloat16*)((char*)Wx1b + (long)HH * HH * 2);
  __hip_bfloat16* Wfcb  = (__hip_bfloat16*)((char*)Wh1b + (long)HH * HH * 2);
  float*          b0sum = (float*)((char*)Wfcb + (long)OUTN * HH * 2);
  float*          b1sum = (float*)((char*)b0sum + HH * 4);
  // total ~151.5 MiB — assumed <= ws_size

  // --- conversions to bf16 ---
  {
    int n4;
    n4 = (Bb * Tt * INN) / 4; cvt4<<<(n4 + 255) / 256, 256, 0, stream>>>(x,   (unsigned short*)xbf,  n4);
    n4 = (HH * INN) / 4;      cvt4<<<(n4 + 255) / 256, 256, 0, stream>>>(Wx0, (unsigned short*)Wx0b, n4);
    n4 = (HH * HH) / 4;       cvt4<<<(n4 + 255) / 256, 256, 0, stream>>>(Wh0, (unsigned short*)Wh0b, n4);
    n4 = (HH * HH) / 4;       cvt4<<<(n4 + 255) / 256, 256, 0, stream>>>(Wx1, (unsigned short*)Wx1b, n4);
    n4 = (HH * HH) / 4;       cvt4<<<(n4 + 255) / 256, 256, 0, stream>>>(Wh1, (unsigned short*)Wh1b, n4);
    n4 = (OUTN * HH) / 4;     cvt4<<<(n4 + 255) / 256, 256, 0, stream>>>(Wfc, (unsigned short*)Wfcb, n4);
    addv<<<4, 256, 0, stream>>>(bx0, bh0, b0sum, HH);
    addv<<<4, 256, 0, stream>>>(bx1, bh1, b1sum, HH);
  }

  const long ldBT = (long)Tt * HH;  // row stride between batches within one timestep slot

  // --- xproj0: (B*T, H) = x @ Wx0^T + b0sum ---
  {
    dim3 g((Bb * Tt) / 16, HH / 64);
    gemm16<MODE_XP><<<g, 64, 0, stream>>>(xbf, (long)INN, Wx0b, INN, b0sum, P0, (long)HH, INN);
  }

  // --- layer 0 recurrence, in-place on P0 ---
  for (int t = 0; t < Tt; ++t) {
    const __hip_bfloat16* Aprev = P0 + (long)(t - 1) * HH;  // h_{t-1} rows stride T*H
    gemm16<MODE_STEP><<<dim3(Bb / 16, HH / 64), 64, 0, stream>>>(
        (t > 0) ? Aprev : P0, ldBT, Wh0b, HH, nullptr,
        P0 + (long)t * HH, ldBT, (t > 0) ? HH : 0);
  }

  // --- xproj1: (B*T, H) = h1 @ Wx1^T + b1sum ---
  {
    dim3 g((Bb * Tt) / 16, HH / 64);
    gemm16<MODE_XP><<<g, 64, 0, stream>>>(P0, (long)HH, Wx1b, HH, b1sum, P1, (long)HH, HH);
  }

  // --- layer 1 recurrence, in-place on P1 ---
  for (int t = 0; t < Tt; ++t) {
    const __hip_bfloat16* Aprev = P1 + (long)(t - 1) * HH;
    gemm16<MODE_STEP><<<dim3(Bb / 16, HH / 64), 64, 0, stream>>>(
        (t > 0) ? Aprev : P1, ldBT, Wh1b, HH, nullptr,
        P1 + (long)t * HH, ldBT, (t > 0) ? HH : 0);
  }

  // --- fc: out (B, OUT) = h2_last @ Wfc^T + bfc  (fp32 out) ---
  {
    dim3 g(Bb / 16, OUTN / 64);
    gemm16<MODE_FC><<<g, 64, 0, stream>>>(P1 + (long)(Tt - 1) * HH, ldBT, Wfcb, HH,
                                          bfc, d_out, (long)OUTN, HH);
  }
}

// Round 2
// 15080.623 us; speedup vs baseline: 1.0455x; 1.0455x over previous
//
#include <hip/hip_runtime.h>
#include <hip/hip_bf16.h>

#define Bb   64
#define Tt   512
#define INN  256
#define HH   1024
#define OUTN 512

#define NCOL 32              // W columns (output units) per recurrence block
#define NBLK (HH / NCOL)     // 32 n-blocks per batch-group
#define MG   16              // batch rows per group
#define NGRP (Bb / MG)       // 4 groups

static_assert((Tt & (Tt - 1)) == 0, "Tt must be pow2 for XPT remap");

typedef __attribute__((ext_vector_type(8))) short bf16x8;
typedef __attribute__((ext_vector_type(4))) float f32x4;

__device__ __forceinline__ unsigned short f2b(float f) {
  unsigned u = __float_as_uint(f);
  u += 0x7FFFu + ((u >> 16) & 1u);
  return (unsigned short)(u >> 16);
}

// fp32 -> bf16 (RNE), vectorized x4
__global__ void cvt4(const float* __restrict__ in, unsigned short* __restrict__ out, int n4) {
  int i = blockIdx.x * blockDim.x + threadIdx.x;
  if (i >= n4) return;
  float4 v = ((const float4*)in)[i];
  ushort4 o;
  o.x = f2b(v.x); o.y = f2b(v.y); o.z = f2b(v.z); o.w = f2b(v.w);
  ((ushort4*)out)[i] = o;
}

__global__ void addv(const float* __restrict__ a, const float* __restrict__ b,
                     float* __restrict__ o, int n) {
  int i = blockIdx.x * blockDim.x + threadIdx.x;
  if (i < n) o[i] = a[i] + b[i];
}

__global__ void zerok(unsigned int* __restrict__ p, int n) {
  int i = blockIdx.x * blockDim.x + threadIdx.x;
  if (i < n) p[i] = 0u;
}

// Generic MFMA GEMM: C[m,n] = sum_k A[m,k] * W[n,k]  (W stored (N,K) row-major)
// One wave per block, 16(M) x 64(N) tile.
// MODE_XP : C_bf16[m*ldc+n]              = acc + bias[n]
// MODE_XPT: C_bf16[((m%T)*B + m/T)*ldc+n]= acc + bias[n]   (row remap (b,t)->(t,b))
// MODE_FC : C_f32 [m*ldc+n]              = acc + bias[n]
enum { MODE_XP = 0, MODE_XPT = 1, MODE_FC = 2 };

template<int MODE>
__global__ void gemm16(const __hip_bfloat16* __restrict__ A, long lda,
                       const __hip_bfloat16* __restrict__ W, int ldw,
                       const float* __restrict__ bias,
                       void* __restrict__ C, long ldc, int nk)
{
  const int l    = threadIdx.x;
  const int m0   = blockIdx.x << 4;
  const int n0   = blockIdx.y << 6;
  const int r16  = l & 15;
  const int koff = (l >> 4) << 3;

  const short* Ap = (const short*)A + (long)(m0 + r16) * lda + koff;
  const short* Wp = (const short*)W;
  const long  w0  = (long)(n0 + r16) * (long)ldw + koff;
  const long  wS  = (long)ldw << 4;

  f32x4 acc0 = {0,0,0,0}, acc1 = {0,0,0,0}, acc2 = {0,0,0,0}, acc3 = {0,0,0,0};

  for (int kc = 0; kc < nk; kc += 32) {
    bf16x8 a  = *(const bf16x8*)(Ap + kc);
    bf16x8 b0 = *(const bf16x8*)(Wp + w0 +          kc);
    bf16x8 b1 = *(const bf16x8*)(Wp + w0 + wS     + kc);
    bf16x8 b2 = *(const bf16x8*)(Wp + w0 + 2 * wS + kc);
    bf16x8 b3 = *(const bf16x8*)(Wp + w0 + 3 * wS + kc);
    acc0 = __builtin_amdgcn_mfma_f32_16x16x32_bf16(a, b0, acc0, 0, 0, 0);
    acc1 = __builtin_amdgcn_mfma_f32_16x16x32_bf16(a, b1, acc1, 0, 0, 0);
    acc2 = __builtin_amdgcn_mfma_f32_16x16x32_bf16(a, b2, acc2, 0, 0, 0);
    acc3 = __builtin_amdgcn_mfma_f32_16x16x32_bf16(a, b3, acc3, 0, 0, 0);
  }

  const int col = l & 15;
  const int rb  = (l >> 4) << 2;

#define EPILOG(FIDX, ACC)                                                     \
  {                                                                           \
    const int n = n0 + (FIDX << 4) + col;                                     \
    _Pragma("unroll")                                                         \
    for (int r = 0; r < 4; ++r) {                                             \
      const int m = m0 + rb + r;                                              \
      long idx;                                                               \
      if constexpr (MODE == MODE_XPT)                                         \
        idx = ((long)(m & (Tt - 1)) * Bb + (m >> 9)) * ldc + n;               \
      else                                                                    \
        idx = (long)m * ldc + n;                                              \
      float v = ACC[r] + bias[n];                                             \
      if constexpr (MODE == MODE_FC)                                          \
        ((float*)C)[idx] = v;                                                 \
      else                                                                    \
        ((unsigned short*)C)[idx] = f2b(v);                                   \
    }                                                                         \
  }

  EPILOG(0, acc0)
  EPILOG(1, acc1)
  EPILOG(2, acc2)
  EPILOG(3, acc3)
#undef EPILOG
}

// Persistent RNN layer: P [T][B][H] bf16 holds xproj on entry; overwritten
// in-place with h_t. Grid (NBLK, NGRP), 128 threads (2 waves).
// Block (j,g): batch rows [g*MG, g*MG+16), output cols [j*NCOL, j*NCOL+32).
// W slice kept in LDS (64 KiB), 16B-slot XOR-swizzled by (row&7) to avoid
// the 16-way ds_read_b128 bank conflict of a [32][1024] row-major tile.
// Cross-block dep (within a group) via device-scope counter per (g,t).
__global__ __launch_bounds__(128) void rnn_layer(
    const __hip_bfloat16* __restrict__ W,
    __hip_bfloat16* __restrict__ P,
    unsigned int* cnt)
{
  __shared__ short Wl[NCOL * HH];   // 64 KiB
  const int tid = threadIdx.x;
  const int l   = tid & 63;
  const int wv  = tid >> 6;         // 0..1
  const int j   = blockIdx.x;
  const int g   = blockIdx.y;
  const int n0  = j * NCOL;

  // Stage W rows [n0, n0+32) into LDS. Physical 16B-slot p of row r holds
  // global slot p ^ (r&7)  (involution: read applies the same XOR).
  for (int idx = tid; idx < NCOL * 128; idx += 128) {
    const int r  = idx >> 7;
    const int p  = idx & 127;
    const int gs = p ^ (r & 7);
    *(bf16x8*)(Wl + r * HH + p * 8) =
        *(const bf16x8*)((const short*)W + (long)(n0 + r) * HH + gs * 8);
  }
  __syncthreads();

  const int rowA = g * MG;
  unsigned int* mycnt = cnt + g * Tt;

  const int fr = l & 15;
  const int ko = (l >> 4) << 3;
  const int rb = (l >> 4) << 2;
  const short* Wrow = Wl + (wv * 16 + fr) * HH;
  const int rx = (wv * 16 + fr) & 7;
  const long Aoff = (long)(rowA + fr) * HH + ko;
  const int ccol = n0 + wv * 16 + fr;

  for (int t = 0; t < Tt; ++t) {
    f32x4 acc = {0, 0, 0, 0};
    if (t > 0) {
      if (tid == 0) {
        int guard = 0;
        while (__hip_atomic_load(&mycnt[t - 1], __ATOMIC_RELAXED,
                                 __HIP_MEMORY_SCOPE_AGENT) < (unsigned)NBLK) {
          __builtin_amdgcn_s_sleep(2);
          if (++guard > 100000000) break;   // fail loud (wrong result), not hang
        }
      }
      __syncthreads();
      __threadfence();   // acquire: invalidate stale L2 before reading h_{t-1}
      const short* Ap = (const short*)P + (long)(t - 1) * (Bb * HH) + Aoff;
      f32x4 acc1 = {0, 0, 0, 0};
      #pragma unroll
      for (int kc = 0; kc < HH; kc += 64) {
        bf16x8 a0 = *(const bf16x8*)(Ap + kc);
        bf16x8 a1 = *(const bf16x8*)(Ap + kc + 32);
        const int s0 = (kc >> 3) + (l >> 4);
        bf16x8 b0 = *(const bf16x8*)(Wrow + (((s0)     ^ rx) << 3));
        bf16x8 b1 = *(const bf16x8*)(Wrow + (((s0 + 4) ^ rx) << 3));
        acc  = __builtin_amdgcn_mfma_f32_16x16x32_bf16(a0, b0, acc,  0, 0, 0);
        acc1 = __builtin_amdgcn_mfma_f32_16x16x32_bf16(a1, b1, acc1, 0, 0, 0);
      }
      acc += acc1;
    }
    // epilogue: h_t = tanh(acc + xproj_t), in place over P[t]
    {
      unsigned short* Pu = (unsigned short*)P;
      const long cbase = ((long)t * Bb + rowA + rb) * HH + ccol;
      #pragma unroll
      for (int r = 0; r < 4; ++r) {
        const long idx2 = cbase + (long)r * HH;
        float v = acc[r] + __bfloat162float(((const __hip_bfloat16*)P)[idx2]);
        Pu[idx2] = f2b(tanhf(v));
      }
    }
    __threadfence();     // release: flush h_t before signaling
    __syncthreads();     // both waves' fences done before flag
    if (tid == 0)
      __hip_atomic_fetch_add(&mycnt[t], 1u, __ATOMIC_RELAXED,
                             __HIP_MEMORY_SCOPE_AGENT);
  }
}

extern "C" void kernel_launch(void* const* d_in, const int* in_sizes, int n_in,
                              void* d_out, int out_size, void* d_ws, size_t ws_size,
                              hipStream_t stream)
{
  const float* x   = (const float*)d_in[0];
  const float* Wx0 = (const float*)d_in[1];
  const float* bx0 = (const float*)d_in[2];
  const float* Wh0 = (const float*)d_in[3];
  const float* bh0 = (const float*)d_in[4];
  const float* Wx1 = (const float*)d_in[5];
  const float* bx1 = (const float*)d_in[6];
  const float* Wh1 = (const float*)d_in[7];
  const float* bh1 = (const float*)d_in[8];
  const float* Wfc = (const float*)d_in[9];
  const float* bfc = (const float*)d_in[10];

  char* ws = (char*)d_ws;
  const long SZ_XBF = (long)Bb * Tt * INN * 2;
  const long SZ_P   = (long)Bb * Tt * HH  * 2;
  __hip_bfloat16* xbf   = (__hip_bfloat16*)(ws);
  __hip_bfloat16* P0    = (__hip_bfloat16*)(ws + SZ_XBF);          // [T][B][H]
  __hip_bfloat16* P1    = (__hip_bfloat16*)(ws + SZ_XBF + SZ_P);   // [T][B][H]
  __hip_bfloat16* Wx0b  = (__hip_bfloat16*)(ws + SZ_XBF + 2 * SZ_P);
  __hip_bfloat16* Wh0b  = (__hip_bfloat16*)((char*)Wx0b + (long)HH * INN * 2);
  __hip_bfloat16* Wx1b  = (__hip_bfloat16*)((char*)Wh0b + (long)HH * HH * 2);
  __hip_bfloat16* Wh1b  = (__hip_bfloat16*)((char*)Wx1b + (long)HH * HH * 2);
  __hip_bfloat16* Wfcb  = (__hip_bfloat16*)((char*)Wh1b + (long)HH * HH * 2);
  float*          b0sum = (float*)((char*)Wfcb + (long)OUTN * HH * 2);
  float*          b1sum = (float*)((char*)b0sum + HH * 4);
  unsigned int*   cnt   = (unsigned int*)((char*)b1sum + HH * 4);  // 2*NGRP*Tt

  // conversions to bf16
  {
    int n4;
    n4 = (Bb * Tt * INN) / 4; cvt4<<<(n4 + 255) / 256, 256, 0, stream>>>(x,   (unsigned short*)xbf,  n4);
    n4 = (HH * INN) / 4;      cvt4<<<(n4 + 255) / 256, 256, 0, stream>>>(Wx0, (unsigned short*)Wx0b, n4);
    n4 = (HH * HH) / 4;       cvt4<<<(n4 + 255) / 256, 256, 0, stream>>>(Wh0, (unsigned short*)Wh0b, n4);
    n4 = (HH * HH) / 4;       cvt4<<<(n4 + 255) / 256, 256, 0, stream>>>(Wx1, (unsigned short*)Wx1b, n4);
    n4 = (HH * HH) / 4;       cvt4<<<(n4 + 255) / 256, 256, 0, stream>>>(Wh1, (unsigned short*)Wh1b, n4);
    n4 = (OUTN * HH) / 4;     cvt4<<<(n4 + 255) / 256, 256, 0, stream>>>(Wfc, (unsigned short*)Wfcb, n4);
    addv<<<4, 256, 0, stream>>>(bx0, bh0, b0sum, HH);
    addv<<<4, 256, 0, stream>>>(bx1, bh1, b1sum, HH);
    zerok<<<(2 * NGRP * Tt + 255) / 256, 256, 0, stream>>>(cnt, 2 * NGRP * Tt);
  }

  // xproj0: rows (b,t) of x -> P0[t][b][:]  (XPT remap), K=256
  gemm16<MODE_XPT><<<dim3((Bb * Tt) / 16, HH / 64), 64, 0, stream>>>(
      xbf, (long)INN, Wx0b, INN, b0sum, P0, (long)HH, INN);

  // layer 0 recurrence (persistent, in-place on P0)
  rnn_layer<<<dim3(NBLK, NGRP), 128, 0, stream>>>(Wh0b, P0, cnt);

  // xproj1: A=P0 rows (t*B+b) natural, K=1024 -> P1 same row order
  gemm16<MODE_XP><<<dim3((Bb * Tt) / 16, HH / 64), 64, 0, stream>>>(
      P0, (long)HH, Wx1b, HH, b1sum, P1, (long)HH, HH);

  // layer 1 recurrence
  rnn_layer<<<dim3(NBLK, NGRP), 128, 0, stream>>>(Wh1b, P1, cnt + NGRP * Tt);

  // fc: h2[T-1] rows contiguous at P1 + (T-1)*B*H
  gemm16<MODE_FC><<<dim3(Bb / 16, OUTN / 64), 64, 0, stream>>>(
      P1 + (long)(Tt - 1) * Bb * HH, (long)HH, Wfcb, HH, bfc, d_out, (long)OUTN, HH);
}

// Round 3
// 11916.778 us; speedup vs baseline: 1.3231x; 1.2655x over previous
//
#include <hip/hip_runtime.h>
#include <hip/hip_bf16.h>

#define Bb   64
#define Tt   512
#define INN  256
#define HH   1024
#define OUTN 512

#define NCOL 32              // W columns (output units) per recurrence block
#define NBLK (HH / NCOL)     // 32 n-blocks per batch-group
#define MG   16              // batch rows per group
#define NGRP (Bb / MG)       // 4 groups
#define NSIG (2 * NBLK)      // per-wave signals per (group, step)

static_assert((Tt & (Tt - 1)) == 0, "Tt must be pow2 for XPT remap");

typedef __attribute__((ext_vector_type(8))) short bf16x8;
typedef __attribute__((ext_vector_type(4))) float f32x4;

__device__ __forceinline__ unsigned short f2b(float f) {
  unsigned u = __float_as_uint(f);
  u += 0x7FFFu + ((u >> 16) & 1u);
  return (unsigned short)(u >> 16);
}

__device__ __forceinline__ unsigned int cohLoadU32(const unsigned int* p) {
  return __hip_atomic_load(p, __ATOMIC_RELAXED, __HIP_MEMORY_SCOPE_AGENT);
}
__device__ __forceinline__ void cohStoreU16(unsigned short* p, unsigned short v) {
  __hip_atomic_store(p, v, __ATOMIC_RELAXED, __HIP_MEMORY_SCOPE_AGENT);
}

// fp32 -> bf16 (RNE), vectorized x4
__global__ void cvt4(const float* __restrict__ in, unsigned short* __restrict__ out, int n4) {
  int i = blockIdx.x * blockDim.x + threadIdx.x;
  if (i >= n4) return;
  float4 v = ((const float4*)in)[i];
  ushort4 o;
  o.x = f2b(v.x); o.y = f2b(v.y); o.z = f2b(v.z); o.w = f2b(v.w);
  ((ushort4*)out)[i] = o;
}

__global__ void addv(const float* __restrict__ a, const float* __restrict__ b,
                     float* __restrict__ o, int n) {
  int i = blockIdx.x * blockDim.x + threadIdx.x;
  if (i < n) o[i] = a[i] + b[i];
}

__global__ void zerok(unsigned int* __restrict__ p, int n) {
  int i = blockIdx.x * blockDim.x + threadIdx.x;
  if (i < n) p[i] = 0u;
}

// Generic MFMA GEMM: C[m,n] = sum_k A[m,k] * W[n,k]  (W stored (N,K) row-major)
// One wave per block, 16(M) x 64(N) tile.
enum { MODE_XP = 0, MODE_XPT = 1, MODE_FC = 2 };

template<int MODE>
__global__ void gemm16(const __hip_bfloat16* __restrict__ A, long lda,
                       const __hip_bfloat16* __restrict__ W, int ldw,
                       const float* __restrict__ bias,
                       void* __restrict__ C, long ldc, int nk)
{
  const int l    = threadIdx.x;
  const int m0   = blockIdx.x << 4;
  const int n0   = blockIdx.y << 6;
  const int r16  = l & 15;
  const int koff = (l >> 4) << 3;

  const short* Ap = (const short*)A + (long)(m0 + r16) * lda + koff;
  const short* Wp = (const short*)W;
  const long  w0  = (long)(n0 + r16) * (long)ldw + koff;
  const long  wS  = (long)ldw << 4;

  f32x4 acc0 = {0,0,0,0}, acc1 = {0,0,0,0}, acc2 = {0,0,0,0}, acc3 = {0,0,0,0};

  for (int kc = 0; kc < nk; kc += 32) {
    bf16x8 a  = *(const bf16x8*)(Ap + kc);
    bf16x8 b0 = *(const bf16x8*)(Wp + w0 +          kc);
    bf16x8 b1 = *(const bf16x8*)(Wp + w0 + wS     + kc);
    bf16x8 b2 = *(const bf16x8*)(Wp + w0 + 2 * wS + kc);
    bf16x8 b3 = *(const bf16x8*)(Wp + w0 + 3 * wS + kc);
    acc0 = __builtin_amdgcn_mfma_f32_16x16x32_bf16(a, b0, acc0, 0, 0, 0);
    acc1 = __builtin_amdgcn_mfma_f32_16x16x32_bf16(a, b1, acc1, 0, 0, 0);
    acc2 = __builtin_amdgcn_mfma_f32_16x16x32_bf16(a, b2, acc2, 0, 0, 0);
    acc3 = __builtin_amdgcn_mfma_f32_16x16x32_bf16(a, b3, acc3, 0, 0, 0);
  }

  const int col = l & 15;
  const int rb  = (l >> 4) << 2;

#define EPILOG(FIDX, ACC)                                                     \
  {                                                                           \
    const int n = n0 + (FIDX << 4) + col;                                     \
    _Pragma("unroll")                                                         \
    for (int r = 0; r < 4; ++r) {                                             \
      const int m = m0 + rb + r;                                              \
      long idx;                                                               \
      if constexpr (MODE == MODE_XPT)                                         \
        idx = ((long)(m & (Tt - 1)) * Bb + (m >> 9)) * ldc + n;               \
      else                                                                    \
        idx = (long)m * ldc + n;                                              \
      float v = ACC[r] + bias[n];                                             \
      if constexpr (MODE == MODE_FC)                                          \
        ((float*)C)[idx] = v;                                                 \
      else                                                                    \
        ((unsigned short*)C)[idx] = f2b(v);                                   \
    }                                                                         \
  }

  EPILOG(0, acc0)
  EPILOG(1, acc1)
  EPILOG(2, acc2)
  EPILOG(3, acc3)
#undef EPILOG
}

// Persistent RNN layer over P [T][B][H] (bf16; xproj on entry, h_t on exit,
// in place). Grid (NBLK, NGRP) x 128 threads (2 waves).
// Block (j,g): batch rows [g*MG, +16), output cols [j*NCOL, +32); wave wv
// owns 16 of the 32 cols. Wh slice resident in LDS (64 KiB, 16B-slot
// XOR-swizzle by row&7). Cross-block h exchange rides the COHERENT path
// (relaxed agent-scope atomics -> L3), so no cache-flush fences anywhere.
// Per-wave signaling: each wave fetch_adds 1 into cnt[g*Tt+t]; waiters poll
// for NSIG. Release order: s_waitcnt vmcnt(0) before the add. Acquire: L3
// serialization (flag response happens-after producer stores reached L3).
__global__ __launch_bounds__(128) void rnn_layer(
    const __hip_bfloat16* __restrict__ W,
    __hip_bfloat16* __restrict__ P,
    unsigned int* cnt)
{
  __shared__ short Wl[NCOL * HH];   // 64 KiB
  const int tid = threadIdx.x;
  const int l   = tid & 63;
  const int wv  = tid >> 6;
  const int j   = blockIdx.x;
  const int g   = blockIdx.y;
  const int n0  = j * NCOL;

  for (int idx = tid; idx < NCOL * 128; idx += 128) {
    const int r  = idx >> 7;
    const int p  = idx & 127;
    const int gs = p ^ (r & 7);
    *(bf16x8*)(Wl + r * HH + p * 8) =
        *(const bf16x8*)((const short*)W + (long)(n0 + r) * HH + gs * 8);
  }
  __syncthreads();   // only barrier in the kernel

  const int rowA = g * MG;
  unsigned int* mycnt = cnt + g * Tt;

  const int fr = l & 15;
  const int ko = (l >> 4) << 3;
  const int rb = (l >> 4) << 2;
  const short* Wrow = Wl + (wv * 16 + fr) * HH;
  const int rx = (wv * 16 + fr) & 7;
  const unsigned int* Pa = (const unsigned int*)P;
  const long AoffU = ((long)(rowA + fr) * HH + ko) >> 1;   // u32 index
  const int ccol = n0 + wv * 16 + fr;
  unsigned short* Pu = (unsigned short*)P;

  union U8 { unsigned int u[4]; bf16x8 v; };

  for (int t = 0; t < Tt; ++t) {
    // xproj for our output tile: block-private, normal cached loads.
    // Issued before the poll so latency hides under the wait.
    const long cbase = ((long)t * Bb + rowA + rb) * HH + ccol;
    float xp[4];
    #pragma unroll
    for (int r = 0; r < 4; ++r)
      xp[r] = __bfloat162float(((const __hip_bfloat16*)P)[cbase + (long)r * HH]);

    f32x4 acc = {0, 0, 0, 0};
    if (t > 0) {
      int guard = 0;
      while (cohLoadU32(&mycnt[t - 1]) < (unsigned)NSIG) {
        __builtin_amdgcn_s_sleep(1);
        if (++guard > 10000000) break;   // fail loud, not hang
      }
      // A = h_{t-1}[rowA+fr][:], coherent u32 loads, fully register-resident
      const unsigned int* Ap = Pa + (((long)(t - 1) * (Bb * HH)) >> 1) + AoffU;
      unsigned int au[128];
      #pragma unroll
      for (int c = 0; c < 16; ++c) {
        #pragma unroll
        for (int q = 0; q < 4; ++q) {
          au[c * 8 + q]     = cohLoadU32(Ap + c * 32 + q);
          au[c * 8 + 4 + q] = cohLoadU32(Ap + c * 32 + 16 + q);
        }
      }
      f32x4 acc1 = {0, 0, 0, 0};
      #pragma unroll
      for (int c = 0; c < 16; ++c) {
        U8 A0, A1;
        #pragma unroll
        for (int q = 0; q < 4; ++q) { A0.u[q] = au[c * 8 + q]; A1.u[q] = au[c * 8 + 4 + q]; }
        const int s0 = (c << 3) + (l >> 4);
        bf16x8 b0 = *(const bf16x8*)(Wrow + (((s0)     ^ rx) << 3));
        bf16x8 b1 = *(const bf16x8*)(Wrow + (((s0 + 4) ^ rx) << 3));
        acc  = __builtin_amdgcn_mfma_f32_16x16x32_bf16(A0.v, b0, acc,  0, 0, 0);
        acc1 = __builtin_amdgcn_mfma_f32_16x16x32_bf16(A1.v, b1, acc1, 0, 0, 0);
      }
      acc += acc1;
    }

    // h_t = tanh(acc + xproj), coherent stores in place over P[t]
    #pragma unroll
    for (int r = 0; r < 4; ++r) {
      float v = acc[r] + xp[r];
      cohStoreU16(Pu + cbase + (long)r * HH, f2b(tanhf(v)));
    }
    asm volatile("s_waitcnt vmcnt(0)" ::: "memory");   // release: stores at L3
    if (l == 0)
      __hip_atomic_fetch_add(&mycnt[t], 1u, __ATOMIC_RELAXED,
                             __HIP_MEMORY_SCOPE_AGENT);
  }
}

extern "C" void kernel_launch(void* const* d_in, const int* in_sizes, int n_in,
                              void* d_out, int out_size, void* d_ws, size_t ws_size,
                              hipStream_t stream)
{
  const float* x   = (const float*)d_in[0];
  const float* Wx0 = (const float*)d_in[1];
  const float* bx0 = (const float*)d_in[2];
  const float* Wh0 = (const float*)d_in[3];
  const float* bh0 = (const float*)d_in[4];
  const float* Wx1 = (const float*)d_in[5];
  const float* bx1 = (const float*)d_in[6];
  const float* Wh1 = (const float*)d_in[7];
  const float* bh1 = (const float*)d_in[8];
  const float* Wfc = (const float*)d_in[9];
  const float* bfc = (const float*)d_in[10];

  char* ws = (char*)d_ws;
  const long SZ_XBF = (long)Bb * Tt * INN * 2;
  const long SZ_P   = (long)Bb * Tt * HH  * 2;
  __hip_bfloat16* xbf   = (__hip_bfloat16*)(ws);
  __hip_bfloat16* P0    = (__hip_bfloat16*)(ws + SZ_XBF);          // [T][B][H]
  __hip_bfloat16* P1    = (__hip_bfloat16*)(ws + SZ_XBF + SZ_P);   // [T][B][H]
  __hip_bfloat16* Wx0b  = (__hip_bfloat16*)(ws + SZ_XBF + 2 * SZ_P);
  __hip_bfloat16* Wh0b  = (__hip_bfloat16*)((char*)Wx0b + (long)HH * INN * 2);
  __hip_bfloat16* Wx1b  = (__hip_bfloat16*)((char*)Wh0b + (long)HH * HH * 2);
  __hip_bfloat16* Wh1b  = (__hip_bfloat16*)((char*)Wx1b + (long)HH * HH * 2);
  __hip_bfloat16* Wfcb  = (__hip_bfloat16*)((char*)Wh1b + (long)HH * HH * 2);
  float*          b0sum = (float*)((char*)Wfcb + (long)OUTN * HH * 2);
  float*          b1sum = (float*)((char*)b0sum + HH * 4);
  unsigned int*   cnt   = (unsigned int*)((char*)b1sum + HH * 4);  // 2*NGRP*Tt

  {
    int n4;
    n4 = (Bb * Tt * INN) / 4; cvt4<<<(n4 + 255) / 256, 256, 0, stream>>>(x,   (unsigned short*)xbf,  n4);
    n4 = (HH * INN) / 4;      cvt4<<<(n4 + 255) / 256, 256, 0, stream>>>(Wx0, (unsigned short*)Wx0b, n4);
    n4 = (HH * HH) / 4;       cvt4<<<(n4 + 255) / 256, 256, 0, stream>>>(Wh0, (unsigned short*)Wh0b, n4);
    n4 = (HH * HH) / 4;       cvt4<<<(n4 + 255) / 256, 256, 0, stream>>>(Wx1, (unsigned short*)Wx1b, n4);
    n4 = (HH * HH) / 4;       cvt4<<<(n4 + 255) / 256, 256, 0, stream>>>(Wh1, (unsigned short*)Wh1b, n4);
    n4 = (OUTN * HH) / 4;     cvt4<<<(n4 + 255) / 256, 256, 0, stream>>>(Wfc, (unsigned short*)Wfcb, n4);
    addv<<<4, 256, 0, stream>>>(bx0, bh0, b0sum, HH);
    addv<<<4, 256, 0, stream>>>(bx1, bh1, b1sum, HH);
    zerok<<<(2 * NGRP * Tt + 255) / 256, 256, 0, stream>>>(cnt, 2 * NGRP * Tt);
  }

  // xproj0: rows (b,t) of x -> P0[t][b][:]  (XPT remap), K=256
  gemm16<MODE_XPT><<<dim3((Bb * Tt) / 16, HH / 64), 64, 0, stream>>>(
      xbf, (long)INN, Wx0b, INN, b0sum, P0, (long)HH, INN);

  // layer 0 recurrence (persistent, in-place on P0)
  rnn_layer<<<dim3(NBLK, NGRP), 128, 0, stream>>>(Wh0b, P0, cnt);

  // xproj1: A=P0 rows (t*B+b), K=1024 -> P1 same row order
  gemm16<MODE_XP><<<dim3((Bb * Tt) / 16, HH / 64), 64, 0, stream>>>(
      P0, (long)HH, Wx1b, HH, b1sum, P1, (long)HH, HH);

  // layer 1 recurrence
  rnn_layer<<<dim3(NBLK, NGRP), 128, 0, stream>>>(Wh1b, P1, cnt + NGRP * Tt);

  // fc: h2[T-1] rows contiguous at P1 + (T-1)*B*H
  gemm16<MODE_FC><<<dim3(Bb / 16, OUTN / 64), 64, 0, stream>>>(
      P1 + (long)(Tt - 1) * Bb * HH, (long)HH, Wfcb, HH, bfc, d_out, (long)OUTN, HH);
}

// Round 4
// 6615.250 us; speedup vs baseline: 2.3834x; 1.8014x over previous
//
#include <hip/hip_runtime.h>
#include <hip/hip_bf16.h>

#define Bb   64
#define Tt   512
#define INN  256
#define HH   1024
#define OUTN 512

#define NCOL 32              // W columns (output units) per recurrence block
#define NBLK (HH / NCOL)     // 32 n-blocks per batch-group
#define MG   16              // batch rows per group
#define NGRP (Bb / MG)       // 4 groups
#define NWAV (2 * NBLK)      // waves (= flags) per group
#define FSTR 8               // flag stride in u32 (32 B)

static_assert((Tt & (Tt - 1)) == 0, "Tt must be pow2 for XPT remap");

typedef __attribute__((ext_vector_type(8))) short bf16x8;
typedef __attribute__((ext_vector_type(4))) float f32x4;

__device__ __forceinline__ unsigned short f2b(float f) {
  unsigned u = __float_as_uint(f);
  u += 0x7FFFu + ((u >> 16) & 1u);
  return (unsigned short)(u >> 16);
}

__device__ __forceinline__ unsigned int cohLoadU32(const unsigned int* p) {
  return __hip_atomic_load(p, __ATOMIC_RELAXED, __HIP_MEMORY_SCOPE_AGENT);
}
__device__ __forceinline__ unsigned long long cohLoadU64(const unsigned long long* p) {
  return __hip_atomic_load(p, __ATOMIC_RELAXED, __HIP_MEMORY_SCOPE_AGENT);
}
__device__ __forceinline__ void cohStoreU16(unsigned short* p, unsigned short v) {
  __hip_atomic_store(p, v, __ATOMIC_RELAXED, __HIP_MEMORY_SCOPE_AGENT);
}
__device__ __forceinline__ void cohStoreU32(unsigned int* p, unsigned int v) {
  __hip_atomic_store(p, v, __ATOMIC_RELAXED, __HIP_MEMORY_SCOPE_AGENT);
}

// fp32 -> bf16 (RNE), vectorized x4
__global__ void cvt4(const float* __restrict__ in, unsigned short* __restrict__ out, int n4) {
  int i = blockIdx.x * blockDim.x + threadIdx.x;
  if (i >= n4) return;
  float4 v = ((const float4*)in)[i];
  ushort4 o;
  o.x = f2b(v.x); o.y = f2b(v.y); o.z = f2b(v.z); o.w = f2b(v.w);
  ((ushort4*)out)[i] = o;
}

__global__ void addv(const float* __restrict__ a, const float* __restrict__ b,
                     float* __restrict__ o, int n) {
  int i = blockIdx.x * blockDim.x + threadIdx.x;
  if (i < n) o[i] = a[i] + b[i];
}

__global__ void zerok(unsigned int* __restrict__ p, int n) {
  int i = blockIdx.x * blockDim.x + threadIdx.x;
  if (i < n) p[i] = 0u;
}

// Generic MFMA GEMM: C[m,n] = sum_k A[m,k] * W[n,k]  (W stored (N,K) row-major)
// One wave per block, 16(M) x 64(N) tile.
enum { MODE_XP = 0, MODE_XPT = 1, MODE_FC = 2 };

template<int MODE>
__global__ void gemm16(const __hip_bfloat16* __restrict__ A, long lda,
                       const __hip_bfloat16* __restrict__ W, int ldw,
                       const float* __restrict__ bias,
                       void* __restrict__ C, long ldc, int nk)
{
  const int l    = threadIdx.x;
  const int m0   = blockIdx.x << 4;
  const int n0   = blockIdx.y << 6;
  const int r16  = l & 15;
  const int koff = (l >> 4) << 3;

  const short* Ap = (const short*)A + (long)(m0 + r16) * lda + koff;
  const short* Wp = (const short*)W;
  const long  w0  = (long)(n0 + r16) * (long)ldw + koff;
  const long  wS  = (long)ldw << 4;

  f32x4 acc0 = {0,0,0,0}, acc1 = {0,0,0,0}, acc2 = {0,0,0,0}, acc3 = {0,0,0,0};

  for (int kc = 0; kc < nk; kc += 32) {
    bf16x8 a  = *(const bf16x8*)(Ap + kc);
    bf16x8 b0 = *(const bf16x8*)(Wp + w0 +          kc);
    bf16x8 b1 = *(const bf16x8*)(Wp + w0 + wS     + kc);
    bf16x8 b2 = *(const bf16x8*)(Wp + w0 + 2 * wS + kc);
    bf16x8 b3 = *(const bf16x8*)(Wp + w0 + 3 * wS + kc);
    acc0 = __builtin_amdgcn_mfma_f32_16x16x32_bf16(a, b0, acc0, 0, 0, 0);
    acc1 = __builtin_amdgcn_mfma_f32_16x16x32_bf16(a, b1, acc1, 0, 0, 0);
    acc2 = __builtin_amdgcn_mfma_f32_16x16x32_bf16(a, b2, acc2, 0, 0, 0);
    acc3 = __builtin_amdgcn_mfma_f32_16x16x32_bf16(a, b3, acc3, 0, 0, 0);
  }

  const int col = l & 15;
  const int rb  = (l >> 4) << 2;

#define EPILOG(FIDX, ACC)                                                     \
  {                                                                           \
    const int n = n0 + (FIDX << 4) + col;                                     \
    _Pragma("unroll")                                                         \
    for (int r = 0; r < 4; ++r) {                                             \
      const int m = m0 + rb + r;                                              \
      long idx;                                                               \
      if constexpr (MODE == MODE_XPT)                                         \
        idx = ((long)(m & (Tt - 1)) * Bb + (m >> 9)) * ldc + n;               \
      else                                                                    \
        idx = (long)m * ldc + n;                                              \
      float v = ACC[r] + bias[n];                                             \
      if constexpr (MODE == MODE_FC)                                          \
        ((float*)C)[idx] = v;                                                 \
      else                                                                    \
        ((unsigned short*)C)[idx] = f2b(v);                                   \
    }                                                                         \
  }

  EPILOG(0, acc0)
  EPILOG(1, acc1)
  EPILOG(2, acc2)
  EPILOG(3, acc3)
#undef EPILOG
}

// Persistent RNN layer over P [T][B][H] (bf16; xproj on entry, h_t on exit,
// in place). Grid (NBLK, NGRP) x 128 threads (2 waves).
// Cross-block h exchange rides the coherent path (relaxed agent atomics ->
// MALL). Signaling is per-WAVE FLAGS (no RMW): wave w of group g stores
// flags[g][w] = t+1 after vmcnt(0); consumers spin on 64 parallel flag
// loads + __all(f >= t). No same-address atomic serialization anywhere.
__global__ __launch_bounds__(128) void rnn_layer(
    const __hip_bfloat16* __restrict__ W,
    __hip_bfloat16* __restrict__ P,
    unsigned int* flags)
{
  __shared__ short Wl[NCOL * HH];   // 64 KiB
  const int tid = threadIdx.x;
  const int l   = tid & 63;
  const int wv  = tid >> 6;
  const int j   = blockIdx.x;
  const int g   = blockIdx.y;
  const int n0  = j * NCOL;

  // Stage W rows [n0, n0+32) into LDS; 16B-slot XOR-swizzle by row&7.
  for (int idx = tid; idx < NCOL * 128; idx += 128) {
    const int r  = idx >> 7;
    const int p  = idx & 127;
    const int gs = p ^ (r & 7);
    *(bf16x8*)(Wl + r * HH + p * 8) =
        *(const bf16x8*)((const short*)W + (long)(n0 + r) * HH + gs * 8);
  }
  __syncthreads();   // only barrier in the kernel

  const int rowA = g * MG;
  unsigned int* gflags = flags + g * (NWAV * FSTR);
  const int wslot = (j * 2 + wv) * FSTR;

  const int fr = l & 15;
  const int lh = l >> 4;
  const int ko = lh << 3;
  const int rb = lh << 2;
  const short* Wrow = Wl + (wv * 16 + fr) * HH;
  const int rx = (wv * 16 + fr) & 7;
  const int ccol = n0 + wv * 16 + fr;
  unsigned short* Pu = (unsigned short*)P;

  union U16 { unsigned long long u[2]; bf16x8 v; };

#define LOADCH(R, CG)                                                         \
  { _Pragma("unroll")                                                         \
    for (int q = 0; q < 4; ++q) {                                             \
      const int cb = ((CG) * 4 + q) * 16;                                     \
      R[q * 4 + 0] = cohLoadU64(Au + cb);                                     \
      R[q * 4 + 1] = cohLoadU64(Au + cb + 1);                                 \
      R[q * 4 + 2] = cohLoadU64(Au + cb + 8);                                 \
      R[q * 4 + 3] = cohLoadU64(Au + cb + 9);                                 \
    } }

#define COMPCH(R, CG)                                                         \
  { _Pragma("unroll")                                                         \
    for (int q = 0; q < 4; ++q) {                                             \
      U16 A0, A1;                                                             \
      A0.u[0] = R[q * 4 + 0]; A0.u[1] = R[q * 4 + 1];                         \
      A1.u[0] = R[q * 4 + 2]; A1.u[1] = R[q * 4 + 3];                         \
      const int s0 = (((CG) * 4 + q) << 3) + lh;                              \
      bf16x8 b0 = *(const bf16x8*)(Wrow + (((s0)     ^ rx) << 3));            \
      bf16x8 b1 = *(const bf16x8*)(Wrow + (((s0 + 4) ^ rx) << 3));            \
      acc  = __builtin_amdgcn_mfma_f32_16x16x32_bf16(A0.v, b0, acc,  0, 0, 0);\
      acc1 = __builtin_amdgcn_mfma_f32_16x16x32_bf16(A1.v, b1, acc1, 0, 0, 0);\
    } }

  for (int t = 0; t < Tt; ++t) {
    // xproj for our output tile (block-private, normal cached loads);
    // issued before the poll so latency hides under the wait.
    const long cbase = ((long)t * Bb + rowA + rb) * HH + ccol;
    float xp[4];
    #pragma unroll
    for (int r = 0; r < 4; ++r)
      xp[r] = __bfloat162float(((const __hip_bfloat16*)P)[cbase + (long)r * HH]);

    f32x4 acc = {0, 0, 0, 0};
    if (t > 0) {
      // wait for all 64 producer waves of this group to finish step t-1
      for (int guard = 0; guard < 2000000; ++guard) {
        unsigned f = cohLoadU32(gflags + l * FSTR);
        if (__all((int)(f >= (unsigned)t))) break;
        __builtin_amdgcn_s_sleep(1);
      }
      const unsigned long long* Au = (const unsigned long long*)
          ((const short*)P + (long)(t - 1) * (Bb * HH) + (long)(rowA + fr) * HH + ko);
      f32x4 acc1 = {0, 0, 0, 0};
      unsigned long long ra[16], rb2[16];
      LOADCH(ra, 0)
      LOADCH(rb2, 1)
      COMPCH(ra, 0)
      LOADCH(ra, 2)
      COMPCH(rb2, 1)
      LOADCH(rb2, 3)
      COMPCH(ra, 2)
      COMPCH(rb2, 3)
      acc += acc1;
    }

    // h_t = tanh(acc + xproj), coherent stores in place over P[t]
    #pragma unroll
    for (int r = 0; r < 4; ++r) {
      float v = acc[r] + xp[r];
      cohStoreU16(Pu + cbase + (long)r * HH, f2b(tanhf(v)));
    }
    asm volatile("s_waitcnt vmcnt(0)" ::: "memory");   // release: h at MALL
    if (l == 0)
      cohStoreU32(gflags + wslot, (unsigned)(t + 1));
  }
#undef LOADCH
#undef COMPCH
}

extern "C" void kernel_launch(void* const* d_in, const int* in_sizes, int n_in,
                              void* d_out, int out_size, void* d_ws, size_t ws_size,
                              hipStream_t stream)
{
  const float* x   = (const float*)d_in[0];
  const float* Wx0 = (const float*)d_in[1];
  const float* bx0 = (const float*)d_in[2];
  const float* Wh0 = (const float*)d_in[3];
  const float* bh0 = (const float*)d_in[4];
  const float* Wx1 = (const float*)d_in[5];
  const float* bx1 = (const float*)d_in[6];
  const float* Wh1 = (const float*)d_in[7];
  const float* bh1 = (const float*)d_in[8];
  const float* Wfc = (const float*)d_in[9];
  const float* bfc = (const float*)d_in[10];

  char* ws = (char*)d_ws;
  const long SZ_XBF = (long)Bb * Tt * INN * 2;
  const long SZ_P   = (long)Bb * Tt * HH  * 2;
  __hip_bfloat16* xbf   = (__hip_bfloat16*)(ws);
  __hip_bfloat16* P0    = (__hip_bfloat16*)(ws + SZ_XBF);          // [T][B][H]
  __hip_bfloat16* P1    = (__hip_bfloat16*)(ws + SZ_XBF + SZ_P);   // [T][B][H]
  __hip_bfloat16* Wx0b  = (__hip_bfloat16*)(ws + SZ_XBF + 2 * SZ_P);
  __hip_bfloat16* Wh0b  = (__hip_bfloat16*)((char*)Wx0b + (long)HH * INN * 2);
  __hip_bfloat16* Wx1b  = (__hip_bfloat16*)((char*)Wh0b + (long)HH * HH * 2);
  __hip_bfloat16* Wh1b  = (__hip_bfloat16*)((char*)Wx1b + (long)HH * HH * 2);
  __hip_bfloat16* Wfcb  = (__hip_bfloat16*)((char*)Wh1b + (long)HH * HH * 2);
  float*          b0sum = (float*)((char*)Wfcb + (long)OUTN * HH * 2);
  float*          b1sum = (float*)((char*)b0sum + HH * 4);
  unsigned int*   flg   = (unsigned int*)((char*)b1sum + HH * 4);  // 2 layers

  const int FLGN = NGRP * NWAV * FSTR;   // u32 per layer

  {
    int n4;
    n4 = (Bb * Tt * INN) / 4; cvt4<<<(n4 + 255) / 256, 256, 0, stream>>>(x,   (unsigned short*)xbf,  n4);
    n4 = (HH * INN) / 4;      cvt4<<<(n4 + 255) / 256, 256, 0, stream>>>(Wx0, (unsigned short*)Wx0b, n4);
    n4 = (HH * HH) / 4;       cvt4<<<(n4 + 255) / 256, 256, 0, stream>>>(Wh0, (unsigned short*)Wh0b, n4);
    n4 = (HH * HH) / 4;       cvt4<<<(n4 + 255) / 256, 256, 0, stream>>>(Wx1, (unsigned short*)Wx1b, n4);
    n4 = (HH * HH) / 4;       cvt4<<<(n4 + 255) / 256, 256, 0, stream>>>(Wh1, (unsigned short*)Wh1b, n4);
    n4 = (OUTN * HH) / 4;     cvt4<<<(n4 + 255) / 256, 256, 0, stream>>>(Wfc, (unsigned short*)Wfcb, n4);
    addv<<<4, 256, 0, stream>>>(bx0, bh0, b0sum, HH);
    addv<<<4, 256, 0, stream>>>(bx1, bh1, b1sum, HH);
    zerok<<<(2 * FLGN + 255) / 256, 256, 0, stream>>>(flg, 2 * FLGN);
  }

  // xproj0: rows (b,t) of x -> P0[t][b][:]  (XPT remap), K=256
  gemm16<MODE_XPT><<<dim3((Bb * Tt) / 16, HH / 64), 64, 0, stream>>>(
      xbf, (long)INN, Wx0b, INN, b0sum, P0, (long)HH, INN);

  // layer 0 recurrence (persistent, in-place on P0)
  rnn_layer<<<dim3(NBLK, NGRP), 128, 0, stream>>>(Wh0b, P0, flg);

  // xproj1: A=P0 rows (t*B+b), K=1024 -> P1 same row order
  gemm16<MODE_XP><<<dim3((Bb * Tt) / 16, HH / 64), 64, 0, stream>>>(
      P0, (long)HH, Wx1b, HH, b1sum, P1, (long)HH, HH);

  // layer 1 recurrence
  rnn_layer<<<dim3(NBLK, NGRP), 128, 0, stream>>>(Wh1b, P1, flg + FLGN);

  // fc: h2[T-1] rows contiguous at P1 + (T-1)*B*H
  gemm16<MODE_FC><<<dim3(Bb / 16, OUTN / 64), 64, 0, stream>>>(
      P1 + (long)(Tt - 1) * Bb * HH, (long)HH, Wfcb, HH, bfc, d_out, (long)OUTN, HH);
}

// Round 5
// 6335.571 us; speedup vs baseline: 2.4886x; 1.0441x over previous
//
#include <hip/hip_runtime.h>
#include <hip/hip_bf16.h>

#define Bb   64
#define Tt   512
#define INN  256
#define HH   1024
#define OUTN 512

#define NCOL 32              // output cols per block
#define NBLK (HH / NCOL)     // 32 n-blocks per group
#define MG   16              // batch rows per group
#define NGRP (Bb / MG)       // 4 groups
#define NWAV (2 * NBLK)      // flag slots per group (one per wave)
#define FSTR 8               // flag stride in u32 (32 B)

typedef __attribute__((ext_vector_type(8))) short bf16x8;
typedef __attribute__((ext_vector_type(4))) float f32x4;

__device__ __forceinline__ unsigned short f2b(float f) {
  unsigned u = __float_as_uint(f);
  u += 0x7FFFu + ((u >> 16) & 1u);
  return (unsigned short)(u >> 16);
}

__device__ __forceinline__ unsigned int cohLoadU32(const unsigned int* p) {
  return __hip_atomic_load(p, __ATOMIC_RELAXED, __HIP_MEMORY_SCOPE_AGENT);
}
__device__ __forceinline__ unsigned long long cohLoadU64(const unsigned long long* p) {
  return __hip_atomic_load(p, __ATOMIC_RELAXED, __HIP_MEMORY_SCOPE_AGENT);
}
__device__ __forceinline__ void cohStoreU16(unsigned short* p, unsigned short v) {
  __hip_atomic_store(p, v, __ATOMIC_RELAXED, __HIP_MEMORY_SCOPE_AGENT);
}
__device__ __forceinline__ void cohStoreU32(unsigned int* p, unsigned int v) {
  __hip_atomic_store(p, v, __ATOMIC_RELAXED, __HIP_MEMORY_SCOPE_AGENT);
}

union U16 { unsigned long long u[2]; bf16x8 v; };

// fp32 -> bf16 (RNE), vectorized x4
__global__ void cvt4(const float* __restrict__ in, unsigned short* __restrict__ out, int n4) {
  int i = blockIdx.x * blockDim.x + threadIdx.x;
  if (i >= n4) return;
  float4 v = ((const float4*)in)[i];
  ushort4 o;
  o.x = f2b(v.x); o.y = f2b(v.y); o.z = f2b(v.z); o.w = f2b(v.w);
  ((ushort4*)out)[i] = o;
}

__global__ void addv(const float* __restrict__ a, const float* __restrict__ b,
                     float* __restrict__ o, int n) {
  int i = blockIdx.x * blockDim.x + threadIdx.x;
  if (i < n) o[i] = a[i] + b[i];
}

__global__ void zerok(unsigned int* __restrict__ p, int n) {
  int i = blockIdx.x * blockDim.x + threadIdx.x;
  if (i < n) p[i] = 0u;
}

// Poll 64 per-wave flags (lane l reads flag l); true when all >= need.
__device__ __forceinline__ bool pollge(const unsigned int* gf, int l, unsigned need) {
  for (int guard = 0; guard < 400000; ++guard) {
    unsigned f = cohLoadU32(gf + l * FSTR);
    if (__all((int)(f >= need))) return true;
    __builtin_amdgcn_s_sleep(1);
  }
  return false;   // fail loud (garbage result), not hang
}

// A-chunk coherent loads: 16 u64 per chunk-group CG (covers K-slice CG*256..+255)
#define LOADCH(R, AU, CG)                                                     \
  { _Pragma("unroll")                                                         \
    for (int q = 0; q < 4; ++q) {                                             \
      const int cb = ((CG) * 4 + q) * 16;                                     \
      R[q * 4 + 0] = cohLoadU64((AU) + cb);                                   \
      R[q * 4 + 1] = cohLoadU64((AU) + cb + 1);                               \
      R[q * 4 + 2] = cohLoadU64((AU) + cb + 8);                               \
      R[q * 4 + 3] = cohLoadU64((AU) + cb + 9);                               \
    } }

// MFMA on one chunk-group; W fragments read straight from global (L2-resident)
#define COMPCH(R, CG, WROW)                                                   \
  { _Pragma("unroll")                                                         \
    for (int q = 0; q < 4; ++q) {                                             \
      U16 A0, A1;                                                             \
      A0.u[0] = R[q * 4 + 0]; A0.u[1] = R[q * 4 + 1];                         \
      A1.u[0] = R[q * 4 + 2]; A1.u[1] = R[q * 4 + 3];                         \
      const int s0 = (((CG) * 4 + q) << 3) + lh;                              \
      bf16x8 b0 = *(const bf16x8*)((WROW) + (s0 << 3));                       \
      bf16x8 b1 = *(const bf16x8*)((WROW) + ((s0 + 4) << 3));                 \
      acc  = __builtin_amdgcn_mfma_f32_16x16x32_bf16(A0.v, b0, acc,  0, 0, 0);\
      acc1 = __builtin_amdgcn_mfma_f32_16x16x32_bf16(A1.v, b1, acc1, 0, 0, 0);\
    } }

// Fused 2-layer persistent RNN. 256 blocks (1/CU), 128 threads (2 waves).
// Blocks 0..127: layer 0 (xproj0 from x fused). Blocks 128..255: layer 1
// (xproj1 from h1_t fused). P0/P1 [T][B][H] hold h1/h2 (coherent stores).
// Per-wave flags; no LDS; W streamed from per-XCD L2.
__global__ __launch_bounds__(128, 1) void rnn_fused(
    const __hip_bfloat16* __restrict__ xs,                       // [B][T][IN]
    const __hip_bfloat16* __restrict__ Wx0, const __hip_bfloat16* __restrict__ Wh0,
    const __hip_bfloat16* __restrict__ Wx1, const __hip_bfloat16* __restrict__ Wh1,
    const float* __restrict__ b0s, const float* __restrict__ b1s,
    __hip_bfloat16* __restrict__ P0, __hip_bfloat16* __restrict__ P1,
    unsigned int* flg0, unsigned int* flg1)
{
  const int tid = threadIdx.x;
  const int l   = tid & 63;
  const int wv  = tid >> 6;
  const int lb  = blockIdx.x;
  const int layer = lb >> 7;
  const int lj  = lb & 127;
  const int j   = lj & 31;
  const int g   = lj >> 5;
  const int n0  = j * NCOL;
  const int rowA = g * MG;

  const int fr = l & 15;
  const int lh = l >> 4;
  const int ko = lh << 3;
  const int rb = lh << 2;
  const int ccol = n0 + wv * 16 + fr;
  const int wr   = ccol;                 // W row this lane supplies
  const int wslot = (j * 2 + wv) * FSTR;

  unsigned int* gf0 = flg0 + g * (NWAV * FSTR);
  unsigned int* gf1 = flg1 + g * (NWAV * FSTR);

  if (layer == 0) {
    const short* Wx0row = (const short*)Wx0 + (long)wr * INN;
    const short* Wh0row = (const short*)Wh0 + (long)wr * HH;
    const float bias = b0s[ccol];
    unsigned short* Pu = (unsigned short*)P0;
    unsigned long long ra[16], rb2[16];

    for (int t = 0; t < Tt; ++t) {
      f32x4 acc = {bias, bias, bias, bias}, acc1 = {0, 0, 0, 0};
      // xp0 = x_t @ Wx0^T (plain cached loads, K=256) — no dependency
      const short* xrow = (const short*)xs + ((long)(rowA + fr) * Tt + t) * INN + ko;
      #pragma unroll
      for (int c = 0; c < 4; ++c) {
        bf16x8 A0 = *(const bf16x8*)(xrow + c * 64);
        bf16x8 A1 = *(const bf16x8*)(xrow + c * 64 + 32);
        bf16x8 b0 = *(const bf16x8*)(Wx0row + ((c * 8 + lh) << 3));
        bf16x8 b1 = *(const bf16x8*)(Wx0row + ((c * 8 + lh + 4) << 3));
        acc  = __builtin_amdgcn_mfma_f32_16x16x32_bf16(A0, b0, acc,  0, 0, 0);
        acc1 = __builtin_amdgcn_mfma_f32_16x16x32_bf16(A1, b1, acc1, 0, 0, 0);
      }
      if (t > 0) {
        if (!pollge(gf0, l, (unsigned)t)) break;
        const unsigned long long* Au = (const unsigned long long*)
            ((const short*)P0 + (long)(t - 1) * (Bb * HH) + (long)(rowA + fr) * HH + ko);
        LOADCH(ra, Au, 0) LOADCH(rb2, Au, 1)
        COMPCH(ra, 0, Wh0row) LOADCH(ra, Au, 2)
        COMPCH(rb2, 1, Wh0row) LOADCH(rb2, Au, 3)
        COMPCH(ra, 2, Wh0row) COMPCH(rb2, 3, Wh0row)
      }
      acc += acc1;
      const long cbase = ((long)t * Bb + rowA + rb) * HH + ccol;
      #pragma unroll
      for (int r = 0; r < 4; ++r)
        cohStoreU16(Pu + cbase + (long)r * HH, f2b(tanhf(acc[r])));
      asm volatile("s_waitcnt vmcnt(0)" ::: "memory");
      if (l == 0) cohStoreU32(gf0 + wslot, (unsigned)(t + 1));
    }
  } else {
    const short* Wx1row = (const short*)Wx1 + (long)wr * HH;
    const short* Wh1row = (const short*)Wh1 + (long)wr * HH;
    const float bias = b1s[ccol];
    unsigned short* Pu = (unsigned short*)P1;
    unsigned long long ra[16], rb2[16];

    for (int t = 0; t < Tt; ++t) {
      f32x4 acc = {bias, bias, bias, bias}, acc1 = {0, 0, 0, 0};
      // wait for h1_t, compute xp1 = h1_t @ Wx1^T (off the h2 critical path)
      if (!pollge(gf0, l, (unsigned)(t + 1))) break;
      {
        const unsigned long long* Au = (const unsigned long long*)
            ((const short*)P0 + (long)t * (Bb * HH) + (long)(rowA + fr) * HH + ko);
        LOADCH(ra, Au, 0) LOADCH(rb2, Au, 1)
        COMPCH(ra, 0, Wx1row) LOADCH(ra, Au, 2)
        COMPCH(rb2, 1, Wx1row) LOADCH(rb2, Au, 3)
        COMPCH(ra, 2, Wx1row) COMPCH(rb2, 3, Wx1row)
      }
      if (t > 0) {
        if (!pollge(gf1, l, (unsigned)t)) break;
        const unsigned long long* Au = (const unsigned long long*)
            ((const short*)P1 + (long)(t - 1) * (Bb * HH) + (long)(rowA + fr) * HH + ko);
        LOADCH(ra, Au, 0) LOADCH(rb2, Au, 1)
        COMPCH(ra, 0, Wh1row) LOADCH(ra, Au, 2)
        COMPCH(rb2, 1, Wh1row) LOADCH(rb2, Au, 3)
        COMPCH(ra, 2, Wh1row) COMPCH(rb2, 3, Wh1row)
      }
      acc += acc1;
      const long cbase = ((long)t * Bb + rowA + rb) * HH + ccol;
      #pragma unroll
      for (int r = 0; r < 4; ++r)
        cohStoreU16(Pu + cbase + (long)r * HH, f2b(tanhf(acc[r])));
      asm volatile("s_waitcnt vmcnt(0)" ::: "memory");
      if (l == 0) cohStoreU32(gf1 + wslot, (unsigned)(t + 1));
    }
  }
}

// fc: out[64][512] = h2_last @ Wfc^T + bfc. One wave per 16x64 tile.
// A-loads coherent (h2 was written via the coherent path; avoids any stale-L2
// hazard across graph replays).
__global__ void fc_kernel(const __hip_bfloat16* __restrict__ A,   // h2_last [B][H]
                          const __hip_bfloat16* __restrict__ W,   // [OUT][H]
                          const float* __restrict__ bias,
                          float* __restrict__ C)
{
  const int l   = threadIdx.x;
  const int m0  = blockIdx.x << 4;
  const int n0  = blockIdx.y << 6;
  const int r16 = l & 15;
  const int lh  = l >> 4;

  const unsigned long long* Au =
      (const unsigned long long*)((const short*)A + (long)(m0 + r16) * HH);
  const short* Wp = (const short*)W;
  const long w0 = (long)(n0 + r16) * HH + (lh << 3);
  const long wS = (long)HH << 4;

  f32x4 acc0 = {0,0,0,0}, acc1 = {0,0,0,0}, acc2 = {0,0,0,0}, acc3 = {0,0,0,0};

  for (int kc = 0; kc < HH; kc += 32) {
    U16 a;
    a.u[0] = cohLoadU64(Au + (kc >> 2) + (lh << 1));
    a.u[1] = cohLoadU64(Au + (kc >> 2) + (lh << 1) + 1);
    bf16x8 b0 = *(const bf16x8*)(Wp + w0 +          kc);
    bf16x8 b1 = *(const bf16x8*)(Wp + w0 + wS     + kc);
    bf16x8 b2 = *(const bf16x8*)(Wp + w0 + 2 * wS + kc);
    bf16x8 b3 = *(const bf16x8*)(Wp + w0 + 3 * wS + kc);
    acc0 = __builtin_amdgcn_mfma_f32_16x16x32_bf16(a.v, b0, acc0, 0, 0, 0);
    acc1 = __builtin_amdgcn_mfma_f32_16x16x32_bf16(a.v, b1, acc1, 0, 0, 0);
    acc2 = __builtin_amdgcn_mfma_f32_16x16x32_bf16(a.v, b2, acc2, 0, 0, 0);
    acc3 = __builtin_amdgcn_mfma_f32_16x16x32_bf16(a.v, b3, acc3, 0, 0, 0);
  }

  const int col = l & 15;
  const int rbb = (l >> 4) << 2;
#define FCEP(FIDX, ACC)                                                       \
  { const int n = n0 + (FIDX << 4) + col;                                     \
    _Pragma("unroll")                                                         \
    for (int r = 0; r < 4; ++r)                                               \
      C[(long)(m0 + rbb + r) * OUTN + n] = ACC[r] + bias[n]; }
  FCEP(0, acc0) FCEP(1, acc1) FCEP(2, acc2) FCEP(3, acc3)
#undef FCEP
}

extern "C" void kernel_launch(void* const* d_in, const int* in_sizes, int n_in,
                              void* d_out, int out_size, void* d_ws, size_t ws_size,
                              hipStream_t stream)
{
  const float* x   = (const float*)d_in[0];
  const float* Wx0 = (const float*)d_in[1];
  const float* bx0 = (const float*)d_in[2];
  const float* Wh0 = (const float*)d_in[3];
  const float* bh0 = (const float*)d_in[4];
  const float* Wx1 = (const float*)d_in[5];
  const float* bx1 = (const float*)d_in[6];
  const float* Wh1 = (const float*)d_in[7];
  const float* bh1 = (const float*)d_in[8];
  const float* Wfc = (const float*)d_in[9];
  const float* bfc = (const float*)d_in[10];

  char* ws = (char*)d_ws;
  const long SZ_XBF = (long)Bb * Tt * INN * 2;
  const long SZ_P   = (long)Bb * Tt * HH  * 2;
  __hip_bfloat16* xbf   = (__hip_bfloat16*)(ws);
  __hip_bfloat16* P0    = (__hip_bfloat16*)(ws + SZ_XBF);          // h1 [T][B][H]
  __hip_bfloat16* P1    = (__hip_bfloat16*)(ws + SZ_XBF + SZ_P);   // h2 [T][B][H]
  __hip_bfloat16* Wx0b  = (__hip_bfloat16*)(ws + SZ_XBF + 2 * SZ_P);
  __hip_bfloat16* Wh0b  = (__hip_bfloat16*)((char*)Wx0b + (long)HH * INN * 2);
  __hip_bfloat16* Wx1b  = (__hip_bfloat16*)((char*)Wh0b + (long)HH * HH * 2);
  __hip_bfloat16* Wh1b  = (__hip_bfloat16*)((char*)Wx1b + (long)HH * HH * 2);
  __hip_bfloat16* Wfcb  = (__hip_bfloat16*)((char*)Wh1b + (long)HH * HH * 2);
  float*          b0sum = (float*)((char*)Wfcb + (long)OUTN * HH * 2);
  float*          b1sum = (float*)((char*)b0sum + HH * 4);
  unsigned int*   flg   = (unsigned int*)((char*)b1sum + HH * 4);

  const int FLGN = NGRP * NWAV * FSTR;   // u32 per layer

  {
    int n4;
    n4 = (Bb * Tt * INN) / 4; cvt4<<<(n4 + 255) / 256, 256, 0, stream>>>(x,   (unsigned short*)xbf,  n4);
    n4 = (HH * INN) / 4;      cvt4<<<(n4 + 255) / 256, 256, 0, stream>>>(Wx0, (unsigned short*)Wx0b, n4);
    n4 = (HH * HH) / 4;       cvt4<<<(n4 + 255) / 256, 256, 0, stream>>>(Wh0, (unsigned short*)Wh0b, n4);
    n4 = (HH * HH) / 4;       cvt4<<<(n4 + 255) / 256, 256, 0, stream>>>(Wx1, (unsigned short*)Wx1b, n4);
    n4 = (HH * HH) / 4;       cvt4<<<(n4 + 255) / 256, 256, 0, stream>>>(Wh1, (unsigned short*)Wh1b, n4);
    n4 = (OUTN * HH) / 4;     cvt4<<<(n4 + 255) / 256, 256, 0, stream>>>(Wfc, (unsigned short*)Wfcb, n4);
    addv<<<4, 256, 0, stream>>>(bx0, bh0, b0sum, HH);
    addv<<<4, 256, 0, stream>>>(bx1, bh1, b1sum, HH);
    zerok<<<(2 * FLGN + 255) / 256, 256, 0, stream>>>(flg, 2 * FLGN);
  }

  // fused 2-layer pipelined recurrence (xprojs computed in-kernel)
  rnn_fused<<<dim3(2 * NBLK * NGRP), 128, 0, stream>>>(
      xbf, Wx0b, Wh0b, Wx1b, Wh1b, b0sum, b1sum, P0, P1, flg, flg + FLGN);

  // fc on h2[T-1]
  fc_kernel<<<dim3(Bb / 16, OUTN / 64), 64, 0, stream>>>(
      P1 + (long)(Tt - 1) * Bb * HH, Wfcb, bfc, (float*)d_out);
}

// Round 6
// 3604.422 us; speedup vs baseline: 4.3743x; 1.7577x over previous
//
#include <hip/hip_runtime.h>
#include <hip/hip_bf16.h>

#define Bb   64
#define Tt   512
#define INN  256
#define HH   1024
#define OUTN 512

#define NCOL 32              // output cols per block
#define MG   16              // batch rows per group
#define NGRP (Bb / MG)       // 4 groups
#define NSLOT 64             // wave flags per (group, stage) = 32 blocks x 2 waves
#define FSTR 8               // flag stride in u32 (32 B)

typedef __attribute__((ext_vector_type(8))) short bf16x8;
typedef __attribute__((ext_vector_type(4))) float f32x4;

__device__ __forceinline__ unsigned short f2b(float f) {
  unsigned u = __float_as_uint(f);
  u += 0x7FFFu + ((u >> 16) & 1u);
  return (unsigned short)(u >> 16);
}
__device__ __forceinline__ float b2f(unsigned short u) {
  return __uint_as_float((unsigned)u << 16);
}

__device__ __forceinline__ unsigned int cohLoadU32(const unsigned int* p) {
  return __hip_atomic_load(p, __ATOMIC_RELAXED, __HIP_MEMORY_SCOPE_AGENT);
}
__device__ __forceinline__ unsigned long long cohLoadU64(const unsigned long long* p) {
  return __hip_atomic_load(p, __ATOMIC_RELAXED, __HIP_MEMORY_SCOPE_AGENT);
}
__device__ __forceinline__ unsigned short cohLoadU16(const unsigned short* p) {
  return __hip_atomic_load(p, __ATOMIC_RELAXED, __HIP_MEMORY_SCOPE_AGENT);
}
__device__ __forceinline__ void cohStoreU16(unsigned short* p, unsigned short v) {
  __hip_atomic_store(p, v, __ATOMIC_RELAXED, __HIP_MEMORY_SCOPE_AGENT);
}
__device__ __forceinline__ void cohStoreU32(unsigned int* p, unsigned int v) {
  __hip_atomic_store(p, v, __ATOMIC_RELAXED, __HIP_MEMORY_SCOPE_AGENT);
}

// Coherent (L1+L2-bypass, MALL-served) pipelined 16B load. Result NOT valid
// until a following s_waitcnt vmcnt(N) (see VMW). Volatile asm ordering keeps
// issue order; counted waits stay correct because all phase VMEM is ours
// (W comes from LDS -> lgkmcnt, a different counter).
__device__ __forceinline__ void aload(bf16x8& d, const short* p) {
  asm volatile("global_load_dwordx4 %0, %1, off sc0 sc1" : "=v"(d) : "v"(p));
}
#define VMW(N)                                                   \
  do {                                                           \
    asm volatile("s_waitcnt vmcnt(" #N ")" ::: "memory");        \
    __builtin_amdgcn_sched_barrier(0);                           \
  } while (0)

__device__ __forceinline__ f32x4 splat4(float v) { f32x4 r = {v, v, v, v}; return r; }

union U16 { unsigned long long u[2]; bf16x8 v; };

// fp32 -> bf16 (RNE), vectorized x4
__global__ void cvt4(const float* __restrict__ in, unsigned short* __restrict__ out, int n4) {
  int i = blockIdx.x * blockDim.x + threadIdx.x;
  if (i >= n4) return;
  float4 v = ((const float4*)in)[i];
  ushort4 o;
  o.x = f2b(v.x); o.y = f2b(v.y); o.z = f2b(v.z); o.w = f2b(v.w);
  ((ushort4*)out)[i] = o;
}

__global__ void addv(const float* __restrict__ a, const float* __restrict__ b,
                     float* __restrict__ o, int n) {
  int i = blockIdx.x * blockDim.x + threadIdx.x;
  if (i < n) o[i] = a[i] + b[i];
}

__global__ void zerok(unsigned int* __restrict__ p, int n) {
  int i = blockIdx.x * blockDim.x + threadIdx.x;
  if (i < n) p[i] = 0u;
}

// Hard-spin poll of 64 per-wave flags (lane l watches slot l).
__device__ __forceinline__ void waitflags(const unsigned int* gf, int l, unsigned need) {
#pragma clang loop unroll(disable)
  for (int guard = 0; guard < 4000000; ++guard) {
    unsigned f = cohLoadU32(gf + l * FSTR);
    if (__all((int)(f >= need))) return;   // fail loud on exhaust, not hang
  }
}

// 8 MFMAs over k-slices [kk0, kk0+8); W fragments from XOR-swizzled LDS.
__device__ __forceinline__ f32x4 comp8(const bf16x8* ab, const short* Wrow,
                                       int rx, int lh, int kk0, f32x4 acc) {
#pragma unroll
  for (int i = 0; i < 8; ++i) {
    const int s = (((kk0 + i) << 2) + lh) ^ rx;
    bf16x8 w = *(const bf16x8*)(Wrow + (s << 3));
    acc = __builtin_amdgcn_mfma_f32_16x16x32_bf16(ab[i], w, acc, 0, 0, 0);
  }
  return acc;
}

// One K=1024 GEMM phase for this lane's 16x16 tile: 32 coherent asm A-loads,
// 2 batches in flight, counted vmcnt, MFMA vs LDS-resident W.
__device__ __forceinline__ f32x4 kphase(const short* Ap, const short* Wrow,
                                        int rx, int lh, f32x4 acc) {
  f32x4 acc2 = {0, 0, 0, 0};
  bf16x8 a0[8], a1[8];
#pragma unroll
  for (int i = 0; i < 8; ++i) aload(a0[i], Ap + i * 32);
#pragma unroll
  for (int i = 0; i < 8; ++i) aload(a1[i], Ap + 256 + i * 32);
  VMW(8);
  acc = comp8(a0, Wrow, rx, lh, 0, acc);
#pragma unroll
  for (int i = 0; i < 8; ++i) aload(a0[i], Ap + 512 + i * 32);
  VMW(8);
  acc2 = comp8(a1, Wrow, rx, lh, 8, acc2);
#pragma unroll
  for (int i = 0; i < 8; ++i) aload(a1[i], Ap + 768 + i * 32);
  VMW(8);
  acc = comp8(a0, Wrow, rx, lh, 16, acc);
  VMW(0);
  acc2 = comp8(a1, Wrow, rx, lh, 24, acc2);
  return acc + acc2;
}

// 3-stage pipelined persistent RNN. 384 blocks (stage = bid%3), 128 thr,
// 64 KiB LDS (W slice, 16B-slot XOR swizzle), 2 blocks/CU co-resident.
//  stage 0 (L0):  h1_t = tanh(Wh0 h1_{t-1} + Wx0 x_t + b0)      -> P0[t], gf0
//  stage 1 (XP1): xp1_t = Wx1 h1_t + b1                         -> P1[t], gfx
//  stage 2 (WH1): h2_t = tanh(Wh1 h2_{t-1} + xp1_t) (in-place)  -> P1[t], gf1
__global__ __launch_bounds__(128) void rnn3(
    const __hip_bfloat16* __restrict__ xs,                        // [B][T][IN]
    const __hip_bfloat16* __restrict__ Wx0, const __hip_bfloat16* __restrict__ Wh0,
    const __hip_bfloat16* __restrict__ Wx1, const __hip_bfloat16* __restrict__ Wh1,
    const float* __restrict__ b0s, const float* __restrict__ b1s,
    __hip_bfloat16* __restrict__ P0, __hip_bfloat16* __restrict__ P1,
    unsigned int* flags)
{
  __shared__ short Wl[NCOL * HH];   // 64 KiB
  const int tid = threadIdx.x;
  const int l   = tid & 63;
  const int wv  = tid >> 6;
  const int bid = blockIdx.x;
  const int stage = bid % 3;
  const int idx = bid / 3;          // 0..127
  const int j   = idx & 31;
  const int g   = idx >> 5;
  const int n0  = j * NCOL;
  const int rowA = g * MG;
  const int fr = l & 15;
  const int lh = l >> 4;
  const int rb = lh << 2;
  const int ccol = n0 + wv * 16 + fr;
  const int rx = (wv * 16 + fr) & 7;

  // Stage this block's 32-row W slice into LDS (16B slot p of row r holds
  // global slot p ^ (r&7); reads apply the same XOR).
  const short* Wg = (const short*)(stage == 0 ? Wh0 : (stage == 1 ? Wx1 : Wh1));
  for (int i = tid; i < NCOL * 128; i += 128) {
    const int r = i >> 7, p = i & 127, gs = p ^ (r & 7);
    *(bf16x8*)(Wl + r * HH + p * 8) = *(const bf16x8*)(Wg + (long)(n0 + r) * HH + gs * 8);
  }
  __syncthreads();
  const short* Wrow = Wl + (wv * 16 + fr) * HH;

  unsigned int* gf0 = flags + (0 * NGRP + g) * (NSLOT * FSTR);
  unsigned int* gfx = flags + (1 * NGRP + g) * (NSLOT * FSTR);
  unsigned int* gf1 = flags + (2 * NGRP + g) * (NSLOT * FSTR);
  const int wslot = (j * 2 + wv) * FSTR;
  const long laneA = (long)(rowA + fr) * HH + (lh << 3);
  unsigned short* P0u = (unsigned short*)P0;
  unsigned short* P1u = (unsigned short*)P1;

  if (stage == 0) {
    const float bias = b0s[ccol];
    const short* xrow = (const short*)xs + (long)(rowA + fr) * (Tt * INN) + (lh << 3);
    const short* Wx0row = (const short*)Wx0 + (long)ccol * INN + (lh << 3);
    bf16x8 wx[8];
#pragma unroll
    for (int c = 0; c < 8; ++c) wx[c] = *(const bf16x8*)(Wx0row + c * 32);
    f32x4 acc = splat4(bias);
#pragma unroll
    for (int c = 0; c < 8; ++c) {   // xp0 for t=0
      bf16x8 a = *(const bf16x8*)(xrow + c * 32);
      acc = __builtin_amdgcn_mfma_f32_16x16x32_bf16(a, wx[c], acc, 0, 0, 0);
    }
    for (int t = 0; t < Tt; ++t) {
      if (t > 0) {
        waitflags(gf0, l, (unsigned)t);
        acc = kphase((const short*)P0 + (long)(t - 1) * (Bb * HH) + laneA, Wrow, rx, lh, acc);
      }
      const long cb = ((long)t * Bb + rowA + rb) * HH + ccol;
#pragma unroll
      for (int r = 0; r < 4; ++r) cohStoreU16(P0u + cb + (long)r * HH, f2b(tanhf(acc[r])));
      asm volatile("s_waitcnt vmcnt(0)" ::: "memory");
      if (l == 0) cohStoreU32(gf0 + wslot, (unsigned)(t + 1));
      if (t + 1 < Tt) {             // xp0 for t+1, in the straggler window
        acc = splat4(bias);
        const short* xr = xrow + (t + 1) * INN;
#pragma unroll
        for (int c = 0; c < 8; ++c) {
          bf16x8 a = *(const bf16x8*)(xr + c * 32);
          acc = __builtin_amdgcn_mfma_f32_16x16x32_bf16(a, wx[c], acc, 0, 0, 0);
        }
      }
    }
  } else if (stage == 1) {
    const float bias = b1s[ccol];
    for (int t = 0; t < Tt; ++t) {
      waitflags(gf0, l, (unsigned)(t + 1));
      f32x4 acc = kphase((const short*)P0 + (long)t * (Bb * HH) + laneA, Wrow, rx, lh,
                         splat4(bias));
      const long cb = ((long)t * Bb + rowA + rb) * HH + ccol;
#pragma unroll
      for (int r = 0; r < 4; ++r) cohStoreU16(P1u + cb + (long)r * HH, f2b(acc[r]));
      asm volatile("s_waitcnt vmcnt(0)" ::: "memory");
      if (l == 0) cohStoreU32(gfx + wslot, (unsigned)(t + 1));
    }
  } else {
    for (int t = 0; t < Tt; ++t) {
      waitflags(gfx, l, (unsigned)(t + 1));
      const long cb = ((long)t * Bb + rowA + rb) * HH + ccol;
      float xb[4];
#pragma unroll
      for (int r = 0; r < 4; ++r)
        xb[r] = b2f(cohLoadU16(P1u + cb + (long)r * HH));   // consumed here -> drained
      f32x4 acc = {0, 0, 0, 0};
      if (t > 0) {
        waitflags(gf1, l, (unsigned)t);
        acc = kphase((const short*)P1 + (long)(t - 1) * (Bb * HH) + laneA, Wrow, rx, lh, acc);
      }
#pragma unroll
      for (int r = 0; r < 4; ++r)
        cohStoreU16(P1u + cb + (long)r * HH, f2b(tanhf(acc[r] + xb[r])));
      asm volatile("s_waitcnt vmcnt(0)" ::: "memory");
      if (l == 0) cohStoreU32(gf1 + wslot, (unsigned)(t + 1));
    }
  }
}

// fc: out[64][512] = h2_last @ Wfc^T + bfc (coherent A reads).
__global__ void fc_kernel(const __hip_bfloat16* __restrict__ A,
                          const __hip_bfloat16* __restrict__ W,
                          const float* __restrict__ bias,
                          float* __restrict__ C)
{
  const int l   = threadIdx.x;
  const int m0  = blockIdx.x << 4;
  const int n0  = blockIdx.y << 6;
  const int r16 = l & 15;
  const int lh  = l >> 4;

  const unsigned long long* Au =
      (const unsigned long long*)((const short*)A + (long)(m0 + r16) * HH);
  const short* Wp = (const short*)W;
  const long w0 = (long)(n0 + r16) * HH + (lh << 3);
  const long wS = (long)HH << 4;

  f32x4 acc0 = {0,0,0,0}, acc1 = {0,0,0,0}, acc2 = {0,0,0,0}, acc3 = {0,0,0,0};
  for (int kc = 0; kc < HH; kc += 32) {
    U16 a;
    a.u[0] = cohLoadU64(Au + (kc >> 2) + (lh << 1));
    a.u[1] = cohLoadU64(Au + (kc >> 2) + (lh << 1) + 1);
    bf16x8 b0 = *(const bf16x8*)(Wp + w0 +          kc);
    bf16x8 b1 = *(const bf16x8*)(Wp + w0 + wS     + kc);
    bf16x8 b2 = *(const bf16x8*)(Wp + w0 + 2 * wS + kc);
    bf16x8 b3 = *(const bf16x8*)(Wp + w0 + 3 * wS + kc);
    acc0 = __builtin_amdgcn_mfma_f32_16x16x32_bf16(a.v, b0, acc0, 0, 0, 0);
    acc1 = __builtin_amdgcn_mfma_f32_16x16x32_bf16(a.v, b1, acc1, 0, 0, 0);
    acc2 = __builtin_amdgcn_mfma_f32_16x16x32_bf16(a.v, b2, acc2, 0, 0, 0);
    acc3 = __builtin_amdgcn_mfma_f32_16x16x32_bf16(a.v, b3, acc3, 0, 0, 0);
  }
  const int col = l & 15;
  const int rbb = (l >> 4) << 2;
#define FCEP(FIDX, ACC)                                                       \
  { const int n = n0 + (FIDX << 4) + col;                                     \
    _Pragma("unroll")                                                         \
    for (int r = 0; r < 4; ++r)                                               \
      C[(long)(m0 + rbb + r) * OUTN + n] = ACC[r] + bias[n]; }
  FCEP(0, acc0) FCEP(1, acc1) FCEP(2, acc2) FCEP(3, acc3)
#undef FCEP
}

extern "C" void kernel_launch(void* const* d_in, const int* in_sizes, int n_in,
                              void* d_out, int out_size, void* d_ws, size_t ws_size,
                              hipStream_t stream)
{
  const float* x   = (const float*)d_in[0];
  const float* Wx0 = (const float*)d_in[1];
  const float* bx0 = (const float*)d_in[2];
  const float* Wh0 = (const float*)d_in[3];
  const float* bh0 = (const float*)d_in[4];
  const float* Wx1 = (const float*)d_in[5];
  const float* bx1 = (const float*)d_in[6];
  const float* Wh1 = (const float*)d_in[7];
  const float* bh1 = (const float*)d_in[8];
  const float* Wfc = (const float*)d_in[9];
  const float* bfc = (const float*)d_in[10];

  char* ws = (char*)d_ws;
  const long SZ_XBF = (long)Bb * Tt * INN * 2;
  const long SZ_P   = (long)Bb * Tt * HH  * 2;
  __hip_bfloat16* xbf   = (__hip_bfloat16*)(ws);
  __hip_bfloat16* P0    = (__hip_bfloat16*)(ws + SZ_XBF);          // h1 [T][B][H]
  __hip_bfloat16* P1    = (__hip_bfloat16*)(ws + SZ_XBF + SZ_P);   // xp1/h2 [T][B][H]
  __hip_bfloat16* Wx0b  = (__hip_bfloat16*)(ws + SZ_XBF + 2 * SZ_P);
  __hip_bfloat16* Wh0b  = (__hip_bfloat16*)((char*)Wx0b + (long)HH * INN * 2);
  __hip_bfloat16* Wx1b  = (__hip_bfloat16*)((char*)Wh0b + (long)HH * HH * 2);
  __hip_bfloat16* Wh1b  = (__hip_bfloat16*)((char*)Wx1b + (long)HH * HH * 2);
  __hip_bfloat16* Wfcb  = (__hip_bfloat16*)((char*)Wh1b + (long)HH * HH * 2);
  float*          b0sum = (float*)((char*)Wfcb + (long)OUTN * HH * 2);
  float*          b1sum = (float*)((char*)b0sum + HH * 4);
  unsigned int*   flg   = (unsigned int*)((char*)b1sum + HH * 4);

  const int FLGN = 3 * NGRP * NSLOT * FSTR;   // 6144 u32

  {
    int n4;
    n4 = (Bb * Tt * INN) / 4; cvt4<<<(n4 + 255) / 256, 256, 0, stream>>>(x,   (unsigned short*)xbf,  n4);
    n4 = (HH * INN) / 4;      cvt4<<<(n4 + 255) / 256, 256, 0, stream>>>(Wx0, (unsigned short*)Wx0b, n4);
    n4 = (HH * HH) / 4;       cvt4<<<(n4 + 255) / 256, 256, 0, stream>>>(Wh0, (unsigned short*)Wh0b, n4);
    n4 = (HH * HH) / 4;       cvt4<<<(n4 + 255) / 256, 256, 0, stream>>>(Wx1, (unsigned short*)Wx1b, n4);
    n4 = (HH * HH) / 4;       cvt4<<<(n4 + 255) / 256, 256, 0, stream>>>(Wh1, (unsigned short*)Wh1b, n4);
    n4 = (OUTN * HH) / 4;     cvt4<<<(n4 + 255) / 256, 256, 0, stream>>>(Wfc, (unsigned short*)Wfcb, n4);
    addv<<<4, 256, 0, stream>>>(bx0, bh0, b0sum, HH);
    addv<<<4, 256, 0, stream>>>(bx1, bh1, b1sum, HH);
    zerok<<<(FLGN + 255) / 256, 256, 0, stream>>>(flg, FLGN);
  }

  rnn3<<<dim3(384), 128, 0, stream>>>(
      xbf, Wx0b, Wh0b, Wx1b, Wh1b, b0sum, b1sum, P0, P1, flg);

  fc_kernel<<<dim3(Bb / 16, OUTN / 64), 64, 0, stream>>>(
      P1 + (long)(Tt - 1) * Bb * HH, Wfcb, bfc, (float*)d_out);
}